// Round 3
// baseline (365.606 us; speedup 1.0000x reference)
//
#include <hip/hip_runtime.h>
#include <hip/hip_bf16.h>
#include <stdint.h>
#include <stddef.h>

#define RNUM   3
#define NNODES 50000
#define ENUM   1000000
#define BATCH  2048
#define INP    256
#define HID    512
#define OUTC   256
#define BN_EPS 1e-5f

typedef __bf16 bf16x8 __attribute__((ext_vector_type(8)));
typedef float  f32x4  __attribute__((ext_vector_type(4)));

__device__ inline unsigned short f2bf(float f) {
    union { float f; unsigned u; } c; c.f = f;
    unsigned u = c.u;
    return (unsigned short)((u + 0x7fffu + ((u >> 16) & 1u)) >> 16);  // RNE
}

__device__ inline uint4 pack8(float4 a, float4 b) {
    uint4 r;
    r.x = (unsigned)f2bf(a.x) | ((unsigned)f2bf(a.y) << 16);
    r.y = (unsigned)f2bf(a.z) | ((unsigned)f2bf(a.w) << 16);
    r.z = (unsigned)f2bf(b.x) | ((unsigned)f2bf(b.y) << 16);
    r.w = (unsigned)f2bf(b.z) | ((unsigned)f2bf(b.w) << 16);
    return r;
}

// ---------------- weight transpose + bf16 convert ----------------
__global__ __launch_bounds__(256) void k_wt(const float* __restrict__ W1,
                                            const float* __restrict__ W2,
                                            unsigned short* __restrict__ W1T,
                                            unsigned short* __restrict__ W2T) {
    __shared__ float T[32][33];
    int z = blockIdx.z;
    const float* W = z ? W2 : W1;
    unsigned short* WT = z ? W2T : W1T;
    int K = z ? HID : INP;
    int N = z ? OUTC : HID;
    int kt = blockIdx.y, nt = blockIdx.x;
    if (kt * 32 >= K || nt * 32 >= N) return;
    int tx = threadIdx.x & 31, ty = threadIdx.x >> 5;
#pragma unroll
    for (int j = 0; j < 4; ++j)
        T[ty + j * 8][tx] = W[(size_t)(kt * 32 + ty + j * 8) * N + nt * 32 + tx];
    __syncthreads();
#pragma unroll
    for (int j = 0; j < 4; ++j)
        WT[(size_t)(nt * 32 + ty + j * 8) * K + kt * 32 + tx] = f2bf(T[tx][ty + j * 8]);
}

// ---------------- prep: inv via binary search + zero all small arrays ----------------
__global__ void k_prep(const int* __restrict__ bn, int* __restrict__ inv,
                       int* __restrict__ appear, float* __restrict__ deg,
                       float* __restrict__ musum, float* __restrict__ sqsum,
                       int* __restrict__ kcount) {
    int i = blockIdx.x * blockDim.x + threadIdx.x;
    if (i < NNODES) {
        int lo = 0, hi = BATCH;
        while (lo < hi) { int mid = (lo + hi) >> 1; if (bn[mid] < i) lo = mid + 1; else hi = mid; }
        inv[i] = (lo < BATCH && bn[lo] == i) ? lo : -1;
    }
    if (i < RNUM * BATCH) { appear[i] = 0; deg[i] = 0.0f; }
    if (i < RNUM * HID)   { musum[i] = 0.0f; sqsum[i] = 0.0f; }
    if (i < RNUM)         kcount[i] = 0;
}

// ---------------- edge mask + compact (z = relation) ----------------
__global__ void k_mask(const int* __restrict__ edge_index, const int* __restrict__ inv,
                       int* __restrict__ appear, int2* __restrict__ edges,
                       int* __restrict__ kcount) {
    int z = blockIdx.z;
    const int* src = edge_index + (size_t)z * 2 * ENUM;
    const int* dst = src + ENUM;
    int2* ed = edges + (size_t)z * ENUM;
    int* app = appear + z * BATCH;
    int stride = gridDim.x * blockDim.x;
    for (int e4 = blockIdx.x * blockDim.x + threadIdx.x; e4 < ENUM / 4; e4 += stride) {
        int4 s4 = ((const int4*)src)[e4];
        int4 d4 = ((const int4*)dst)[e4];
        int ss[4] = {s4.x, s4.y, s4.z, s4.w};
        int dd[4] = {d4.x, d4.y, d4.z, d4.w};
#pragma unroll
        for (int i = 0; i < 4; ++i) {
            int ps = inv[ss[i]];
            int pd = inv[dd[i]];
            if (ps >= 0 && pd >= 0) {
                int idx = atomicAdd(kcount + z, 1);
                ed[idx] = make_int2(ps, pd);
                app[ps] = 1;
                app[pd] = 1;
            }
        }
    }
}

// ---------------- fused: rank scan + edge remap + degree (one block per relation) ----
__global__ __launch_bounds__(1024) void k_scanDeg(const int* __restrict__ appear,
                                                  int2* __restrict__ edges,
                                                  const int* __restrict__ kcount,
                                                  float* __restrict__ deg) {
    __shared__ int buf[2][BATCH];
    __shared__ float degs[BATCH];
    int z = blockIdx.x;
    const int* ap = appear + z * BATCH;
    int2* ed = edges + (size_t)z * ENUM;
    float* dg = deg + z * BATCH;
    int t = threadIdx.x;
    buf[0][t] = ap[t];
    buf[0][t + 1024] = ap[t + 1024];
    degs[t] = 0.0f; degs[t + 1024] = 0.0f;
    __syncthreads();
    int cur = 0;
    for (int off = 1; off < BATCH; off <<= 1) {
        int nxt = cur ^ 1;
        int i1 = t, i2 = t + 1024;
        buf[nxt][i1] = buf[cur][i1] + (i1 >= off ? buf[cur][i1 - off] : 0);
        buf[nxt][i2] = buf[cur][i2] + (i2 >= off ? buf[cur][i2 - off] : 0);
        __syncthreads();
        cur = nxt;
    }
    int K = kcount[z];
    for (int e = t; e < K; e += 1024) {
        int2 E = ed[e];
        int s = buf[cur][E.x] - 1;
        int d = buf[cur][E.y] - 1;
        ed[e] = make_int2(s, d);
        atomicAdd(&degs[d], 1.0f);
    }
    __syncthreads();
    dg[t] = degs[t];
    dg[t + 1024] = degs[t + 1024];
}

// ---------------- GEMM1: xw = gather(feat, bn) @ W1 ; hbase = xw/(deg+1) + b1 -------
__global__ __launch_bounds__(256) void k_gemm1(
    const float* __restrict__ features, const int* __restrict__ bn,
    const unsigned short* __restrict__ W1T, const float* __restrict__ b1,
    const float* __restrict__ deg, float* __restrict__ xw, float* __restrict__ hbase) {
    __shared__ __align__(16) unsigned short As[64][40];
    __shared__ __align__(16) unsigned short Bs[64][40];
    int z = blockIdx.z;
    const float* feat = features + (size_t)z * NNODES * INP;
    const float* dgz = deg + z * BATCH;
    float* xwz = xw + (size_t)z * BATCH * HID;
    float* hbz = hbase + (size_t)z * BATCH * HID;
    int m0 = blockIdx.y * 64, n0 = blockIdx.x * 64;
    int t = threadIdx.x;
    int ar = t >> 2, aq = t & 3;
    int grow = bn[m0 + ar];
    const float* aptr = feat + (size_t)grow * INP + aq * 8;
    const unsigned short* bptr = W1T + (size_t)(n0 + ar) * INP + aq * 8;

    int lane = t & 63, wave = t >> 6;
    int wm = (wave & 1) * 32, wn = (wave >> 1) * 32;
    int ml = lane & 15, quad = lane >> 4, q8 = quad * 8;

    f32x4 acc[2][2] = {};
    for (int k0 = 0; k0 < INP; k0 += 32) {
        float4 a0 = *(const float4*)(aptr + k0);
        float4 a1 = *(const float4*)(aptr + k0 + 4);
        uint4 bv = *(const uint4*)(bptr + k0);
        *(uint4*)&As[ar][aq * 8] = pack8(a0, a1);
        *(uint4*)&Bs[ar][aq * 8] = bv;
        __syncthreads();
        bf16x8 af[2], bfr[2];
#pragma unroll
        for (int mi = 0; mi < 2; ++mi) af[mi]  = *(const bf16x8*)&As[wm + mi * 16 + ml][q8];
#pragma unroll
        for (int ni = 0; ni < 2; ++ni) bfr[ni] = *(const bf16x8*)&Bs[wn + ni * 16 + ml][q8];
#pragma unroll
        for (int mi = 0; mi < 2; ++mi)
#pragma unroll
            for (int ni = 0; ni < 2; ++ni)
                acc[mi][ni] = __builtin_amdgcn_mfma_f32_16x16x32_bf16(af[mi], bfr[ni], acc[mi][ni], 0, 0, 0);
        __syncthreads();
    }
#pragma unroll
    for (int mi = 0; mi < 2; ++mi)
#pragma unroll
        for (int r = 0; r < 4; ++r) {
            int row = m0 + wm + mi * 16 + quad * 4 + r;
            float d2 = 1.0f / (dgz[row] + 1.0f);
#pragma unroll
            for (int ni = 0; ni < 2; ++ni) {
                int col = n0 + wn + ni * 16 + ml;
                float c = acc[mi][ni][r];
                xwz[(size_t)row * HID + col] = c;
                hbz[(size_t)row * HID + col] = d2 * c + b1[col];
            }
        }
}

// ---------------- GEMM2: BN folded in prologue; out = yw/(deg+1) + b2 ----------------
__global__ __launch_bounds__(256) void k_gemm2(
    const float* __restrict__ hbase, const float* __restrict__ musum,
    const float* __restrict__ sqsum, const float* __restrict__ gamma,
    const float* __restrict__ beta, const unsigned short* __restrict__ W2T,
    const float* __restrict__ b2, const float* __restrict__ deg,
    float* __restrict__ yw, float* __restrict__ out) {
    __shared__ __align__(16) unsigned short As[64][40];
    __shared__ __align__(16) unsigned short Bs[64][40];
    __shared__ __align__(16) float gs[HID];
    __shared__ __align__(16) float ss_[HID];
    int z = blockIdx.z;
    const float* hz = hbase + (size_t)z * BATCH * HID;
    const float* dgz = deg + z * BATCH;
    float* ywz = yw + (size_t)z * BATCH * OUTC;
    float* oz = out + (size_t)z * BATCH * OUTC;
    int m0 = blockIdx.y * 64, n0 = blockIdx.x * 64;
    int t = threadIdx.x;

    // BN finalization (recomputed per block, cheap)
#pragma unroll
    for (int c = t; c < HID; c += 256) {
        float mu = musum[z * HID + c] * (1.0f / BATCH);
        float ex2 = sqsum[z * HID + c] * (1.0f / BATCH);
        float var = ex2 - mu * mu;
        float g = rsqrtf(var + BN_EPS) * gamma[c];
        gs[c] = g;
        ss_[c] = beta[c] - mu * g;
    }
    __syncthreads();

    int ar = t >> 2, aq = t & 3;
    const float* aptr = hz + (size_t)(m0 + ar) * HID + aq * 8;
    const unsigned short* bptr = W2T + (size_t)(n0 + ar) * HID + aq * 8;

    int lane = t & 63, wave = t >> 6;
    int wm = (wave & 1) * 32, wn = (wave >> 1) * 32;
    int ml = lane & 15, quad = lane >> 4, q8 = quad * 8;

    f32x4 acc[2][2] = {};
    for (int k0 = 0; k0 < HID; k0 += 32) {
        float4 h0 = *(const float4*)(aptr + k0);
        float4 h1 = *(const float4*)(aptr + k0 + 4);
        float4 g0 = *(const float4*)(gs + k0 + aq * 8);
        float4 g1 = *(const float4*)(gs + k0 + aq * 8 + 4);
        float4 s0 = *(const float4*)(ss_ + k0 + aq * 8);
        float4 s1 = *(const float4*)(ss_ + k0 + aq * 8 + 4);
        float4 a0 = make_float4(h0.x * g0.x + s0.x, h0.y * g0.y + s0.y,
                                h0.z * g0.z + s0.z, h0.w * g0.w + s0.w);
        float4 a1 = make_float4(h1.x * g1.x + s1.x, h1.y * g1.y + s1.y,
                                h1.z * g1.z + s1.z, h1.w * g1.w + s1.w);
        uint4 bv = *(const uint4*)(bptr + k0);
        *(uint4*)&As[ar][aq * 8] = pack8(a0, a1);
        *(uint4*)&Bs[ar][aq * 8] = bv;
        __syncthreads();
        bf16x8 af[2], bfr[2];
#pragma unroll
        for (int mi = 0; mi < 2; ++mi) af[mi]  = *(const bf16x8*)&As[wm + mi * 16 + ml][q8];
#pragma unroll
        for (int ni = 0; ni < 2; ++ni) bfr[ni] = *(const bf16x8*)&Bs[wn + ni * 16 + ml][q8];
#pragma unroll
        for (int mi = 0; mi < 2; ++mi)
#pragma unroll
            for (int ni = 0; ni < 2; ++ni)
                acc[mi][ni] = __builtin_amdgcn_mfma_f32_16x16x32_bf16(af[mi], bfr[ni], acc[mi][ni], 0, 0, 0);
        __syncthreads();
    }
#pragma unroll
    for (int mi = 0; mi < 2; ++mi)
#pragma unroll
        for (int r = 0; r < 4; ++r) {
            int row = m0 + wm + mi * 16 + quad * 4 + r;
            float d2 = 1.0f / (dgz[row] + 1.0f);
#pragma unroll
            for (int ni = 0; ni < 2; ++ni) {
                int col = n0 + wn + ni * 16 + ml;
                float c = acc[mi][ni][r];
                ywz[(size_t)row * OUTC + col] = c;
                oz[(size_t)row * OUTC + col] = d2 * c + b2[col];
            }
        }
}

// ---------------- edge aggregation (scatter-add, float4 loads) ----------------
__global__ void k_agg(const int2* __restrict__ edges, const int* __restrict__ kcount,
                      const float* __restrict__ deg, const float* __restrict__ src_mat,
                      float* __restrict__ dst_mat, int ncol) {
    int z = blockIdx.z;
    int K = kcount[z];
    const int2* ed = edges + (size_t)z * ENUM;
    const float* dgz = deg + z * BATCH;
    const float* sm = src_mat + (size_t)z * BATCH * ncol;
    float* dm = dst_mat + (size_t)z * BATCH * ncol;
    int nq = ncol >> 2;  // float4 count per row
    for (int e = blockIdx.x; e < K; e += gridDim.x) {
        int2 E = ed[e];
        float w = rsqrtf(dgz[E.x] + 1.0f) * rsqrtf(dgz[E.y] + 1.0f);
        const float4* srow = (const float4*)(sm + (size_t)E.x * ncol);
        float* drow = dm + (size_t)E.y * ncol;
        for (int q = threadIdx.x; q < nq; q += blockDim.x) {
            float4 v = srow[q];
            atomicAdd(&drow[q * 4 + 0], w * v.x);
            atomicAdd(&drow[q * 4 + 1], w * v.y);
            atomicAdd(&drow[q * 4 + 2], w * v.z);
            atomicAdd(&drow[q * 4 + 3], w * v.w);
        }
    }
}

// ---------------- batch norm stats ----------------
__global__ __launch_bounds__(256) void k_bnstats(const float* __restrict__ hbase,
                                                 float* __restrict__ musum,
                                                 float* __restrict__ sqsum) {
    int z = blockIdx.z;
    const float* h = hbase + (size_t)z * BATCH * HID;
    int c0 = threadIdx.x;
    int r0 = blockIdx.x * 32;
    float s1a = 0, s2a = 0, s1b = 0, s2b = 0;
    for (int rr = 0; rr < 32; ++rr) {
        const float* row = h + (size_t)(r0 + rr) * HID;
        float va = row[c0];
        float vb = row[c0 + 256];
        s1a += va; s2a += va * va;
        s1b += vb; s2b += vb * vb;
    }
    atomicAdd(&musum[z * HID + c0], s1a);       atomicAdd(&sqsum[z * HID + c0], s2a);
    atomicAdd(&musum[z * HID + c0 + 256], s1b); atomicAdd(&sqsum[z * HID + c0 + 256], s2b);
}

// ---------------- launch ----------------
extern "C" void kernel_launch(void* const* d_in, const int* in_sizes, int n_in,
                              void* d_out, int out_size, void* d_ws, size_t ws_size,
                              hipStream_t stream) {
    const float* features    = (const float*)d_in[0];
    const float* W1          = (const float*)d_in[1];
    const float* b1          = (const float*)d_in[2];
    const float* W2          = (const float*)d_in[3];
    const float* b2          = (const float*)d_in[4];
    const float* gamma       = (const float*)d_in[5];
    const float* beta        = (const float*)d_in[6];
    const int*   edge_index  = (const int*)d_in[7];
    const int*   batch_nodes = (const int*)d_in[8];
    float* out = (float*)d_out;

    char* p = (char*)d_ws;
    size_t cur = 0;
    auto alloc = [&](size_t bytes) {
        void* r = p + cur;
        cur = (cur + bytes + 255) & ~(size_t)255;
        return r;
    };
    int*   inv    = (int*)  alloc(NNODES * sizeof(int));
    int*   appear = (int*)  alloc(RNUM * BATCH * sizeof(int));
    int*   kcount = (int*)  alloc(RNUM * sizeof(int));
    float* deg    = (float*)alloc(RNUM * BATCH * sizeof(float));
    float* musum  = (float*)alloc(RNUM * HID * sizeof(float));
    float* sqsum  = (float*)alloc(RNUM * HID * sizeof(float));
    unsigned short* W1T = (unsigned short*)alloc((size_t)HID * INP * sizeof(unsigned short));
    unsigned short* W2T = (unsigned short*)alloc((size_t)OUTC * HID * sizeof(unsigned short));
    int2*  edges  = (int2*) alloc((size_t)RNUM * ENUM * sizeof(int2));
    float* xw     = (float*)alloc((size_t)RNUM * BATCH * HID * sizeof(float));
    float* hbase  = (float*)alloc((size_t)RNUM * BATCH * HID * sizeof(float));
    float* yw     = (float*)alloc((size_t)RNUM * BATCH * OUTC * sizeof(float));
    (void)ws_size; (void)in_sizes; (void)n_in; (void)out_size;

    k_wt<<<dim3(16, 16, 2), 256, 0, stream>>>(W1, W2, W1T, W2T);
    k_prep<<<(NNODES + 255) / 256, 256, 0, stream>>>(batch_nodes, inv, appear, deg,
                                                     musum, sqsum, kcount);
    k_mask<<<dim3(512, 1, RNUM), 256, 0, stream>>>(edge_index, inv, appear, edges, kcount);
    k_scanDeg<<<RNUM, 1024, 0, stream>>>(appear, edges, kcount, deg);

    k_gemm1<<<dim3(HID / 64, BATCH / 64, RNUM), 256, 0, stream>>>(
        features, batch_nodes, W1T, b1, deg, xw, hbase);
    k_agg<<<dim3(256, 1, RNUM), 256, 0, stream>>>(edges, kcount, deg, xw, hbase, HID);

    k_bnstats<<<dim3(64, 1, RNUM), 256, 0, stream>>>(hbase, musum, sqsum);

    k_gemm2<<<dim3(OUTC / 64, BATCH / 64, RNUM), 256, 0, stream>>>(
        hbase, musum, sqsum, gamma, beta, W2T, b2, deg, yw, out);
    k_agg<<<dim3(256, 1, RNUM), 256, 0, stream>>>(edges, kcount, deg, yw, out, OUTC);
}